// Round 11
// baseline (2245.839 us; speedup 1.0000x reference)
//
#include <hip/hip_runtime.h>
#include <hip/hip_fp16.h>
#include <cstdint>
#include <cstddef>

#define B_ 128
#define T_ 2048
#define C_ 16
#define CO_ 128
#define H_ 128
#define G_ 512
#define WCV 232                 // conv/x0 worker blocks
#define NBLK (24 + WCV)         // 256 = 8 L0 + 8 Z1 + 8 L1 + workers
#define L2E  1.4426950408889634f
#define L2E2 2.8853900817779268f

typedef _Float16 half8 __attribute__((ext_vector_type(8)));
typedef float f32x4 __attribute__((ext_vector_type(4)));

__device__ __forceinline__ unsigned packh2f(float a, float b) {
  union { _Float16 h[2]; unsigned u; } x;
  x.h[0] = (_Float16)a; x.h[1] = (_Float16)b;
  return x.u;
}

__device__ __forceinline__ float rcpf(float x) { return __builtin_amdgcn_rcpf(x); }

__device__ __forceinline__ float exp2f_(float x) {
#if __has_builtin(__builtin_amdgcn_exp2f)
  return __builtin_amdgcn_exp2f(x);
#else
  return __expf(x * 0.6931471805599453f);
#endif
}

// Soft barrier: LDS-visibility only (global prefetches stay in flight).
__device__ __forceinline__ void softbar() {
  asm volatile("s_waitcnt lgkmcnt(0)\n\ts_barrier" ::: "memory");
}
__device__ __forceinline__ void vmdrain() {
  asm volatile("s_waitcnt vmcnt(0)" ::: "memory");
}

// Gates arrive PRE-SCALED: i,f,o by log2e; g by 2*log2e.
__device__ __forceinline__ void lstm_cell(const f32x4* acc, f32x4& c, float* h) {
#pragma unroll
  for (int r = 0; r < 4; ++r) {
    float iv = acc[0][r], fv = acc[1][r], gv = acc[2][r], ov = acc[3][r];
    gv = fminf(fmaxf(gv, -43.3f), 43.3f);
    float ei = exp2f_(-iv), ef = exp2f_(-fv), eg = exp2f_(gv);
    float P = (1.f + ei) * (eg + 1.f);
    float Q = 1.f + ef;
    float num = c[r] * P + (eg - 1.f) * Q;
    float cN = num * rcpf(Q * P);
    c[r] = cN;
    float cc = fminf(fmaxf(cN, -15.f), 15.f);
    float eo = exp2f_(-ov), ec = exp2f_(L2E2 * cc);
    h[r] = (ec - 1.f) * rcpf((1.f + eo) * (ec + 1.f));
  }
}

// ---------------------------------------------------------------------------
// pack_kernel: fragment-ordered weight buffers (pre-scaled by log2e / 2log2e).
// ---------------------------------------------------------------------------
__global__ __launch_bounds__(256) void pack_kernel(
    const float* __restrict__ w_ih0, const float* __restrict__ w_hh0,
    const float* __restrict__ w_ih1, const float* __restrict__ w_hh1,
    const float* __restrict__ b_ih1, const float* __restrict__ b_hh1,
    uint4* __restrict__ Wf0, uint4* __restrict__ Wih1f,
    uint4* __restrict__ Whh1f, uint4* __restrict__ WB0f,
    f32x4* __restrict__ b1fD) {
  int tid = blockIdx.x * 256 + threadIdx.x;
  if (tid < 24576) {
    int u = tid & 8191, L = u & 63, s = (u >> 6) & 3, tl = (u >> 8) & 3, w = u >> 10;
    int which = tid >> 13;
    const float* src = (which == 0) ? w_hh0 : (which == 1) ? w_ih1 : w_hh1;
    uint4* dst = (which == 0) ? Wf0 : (which == 1) ? Wih1f : Whh1f;
    int m = (w + 8 * tl) * 16 + (L & 15);
    float sc = (tl == 2) ? L2E2 : L2E;
    int k0 = s * 32 + (L >> 4) * 8;
    const float* p = src + m * 128 + k0;
    uint4 o;
    o.x = packh2f(p[0] * sc, p[1] * sc); o.y = packh2f(p[2] * sc, p[3] * sc);
    o.z = packh2f(p[4] * sc, p[5] * sc); o.w = packh2f(p[6] * sc, p[7] * sc);
    dst[u] = o;
  } else if (tid < 32768) {
    int u = tid - 24576, L = u & 63, s = (u >> 6) & 3, nt = u >> 8;
    int g = nt * 16 + (L & 15);
    float sc = ((nt >> 3) == 2) ? L2E2 : L2E;
    int k0 = s * 32 + (L >> 4) * 8;
    const float* p = w_ih0 + g * 128 + k0;
    uint4 o;
    o.x = packh2f(p[0] * sc, p[1] * sc); o.y = packh2f(p[2] * sc, p[3] * sc);
    o.z = packh2f(p[4] * sc, p[5] * sc); o.w = packh2f(p[6] * sc, p[7] * sc);
    WB0f[u] = o;
  } else if (tid < 34816) {
    int u2 = tid - 32768;
    int tl = u2 & 3, L = (u2 >> 2) & 63, w = u2 >> 8;
    int q = L >> 4;
    float sc = (tl == 2) ? L2E2 : L2E;
    f32x4 o;
#pragma unroll
    for (int reg = 0; reg < 4; ++reg) {
      int row = (w + 8 * tl) * 16 + q * 4 + reg;
      o[reg] = (b_ih1[row] + b_hh1[row]) * sc;
    }
    b1fD[u2] = o;
  }
}

// ---------------------------------------------------------------------------
// persist_kernel — R10 structure. The ONLY change vs R10: occupancy_pad_
// inflates static LDS past 160KB/2 so exactly ONE block fits per CU.
// Role blocks (L0/Z1/L1) get exclusive CUs — previously two 44KB/128-VGPR
// blocks co-scheduled per CU, doubling each role CU's per-step issue load.
// ---------------------------------------------------------------------------
__global__ __launch_bounds__(512, 2) void persist_kernel(
    const float* __restrict__ x, const float* __restrict__ conv_w,
    const float* __restrict__ conv_b, const float* __restrict__ b_ih0,
    const float* __restrict__ b_hh0,
    const uint4* __restrict__ Wf0, const uint4* __restrict__ Wih1f,
    const uint4* __restrict__ Whh1f, const uint4* __restrict__ WB0f,
    const f32x4* __restrict__ b1fD,
    uint4* __restrict__ x0f, uint2* __restrict__ h0g, uint4* __restrict__ z1f,
    f32x4* __restrict__ psave, int* __restrict__ flags,
    int rmask, int rmask2) {
  __shared__ __align__(16) union {
    struct { float xs[34 * 16]; _Float16 yh[32 * 136]; _Float16 x0S[32 * 512]; } wk;
    struct { _Float16 h[2][16 * 136]; } rc;
    char occupancy_pad_[84992];  // > 163840/2: forces 1 block/CU (gfx950 160KB LDS)
  } sm;

  int* xready = flags;          // [tile*8 + b16], 512 ints
  int* l0p = flags + 512;       // + b16*16
  int* l0c = flags + 640;       // + b16*16
  int* z1p = flags + 768;       // + b16*16
  int* l1p = flags + 896;       // + b16*16

  const int bid = blockIdx.x;
  const int tid = threadIdx.x;
  const int w = tid >> 6, L = tid & 63, q = L >> 4, n = L & 15;

  if (bid < 8) {
    // ---------------- L0: layer-0 recurrence ----------------
    const int b16 = bid;
    half8 WA0[4][4];
#pragma unroll
    for (int tl = 0; tl < 4; ++tl)
#pragma unroll
      for (int s = 0; s < 4; ++s)
        WA0[tl][s] = __builtin_bit_cast(half8, Wf0[((w * 4 + tl) * 4 + s) * 64 + L]);

    f32x4 c0v = {0.f, 0.f, 0.f, 0.f};
    const int hoff = n * 136 + w * 16 + q * 4;
    *(uint2*)&sm.rc.h[1][hoff] = make_uint2(0u, 0u);
    __syncthreads();

    const uint4* xp = x0f + (((size_t)b16 * 8 + w) * 64 + L) * 2;
    uint2* hg = h0g + ((b16 * 16 + n) * 32 + w * 4 + q);
    uint4 pa[4], pb[4];

    for (int g = 0; g < 64; ++g) {
      if (tid == 0) {
        while (__hip_atomic_load(&xready[g * 8 + b16], __ATOMIC_ACQUIRE,
                                 __HIP_MEMORY_SCOPE_AGENT) < 16)
          __builtin_amdgcn_s_sleep(2);
        if (g < 63)
          while (__hip_atomic_load(&xready[(g + 1) * 8 + b16], __ATOMIC_ACQUIRE,
                                   __HIP_MEMORY_SCOPE_AGENT) < 16)
            __builtin_amdgcn_s_sleep(2);
      }
      __syncthreads();
      if (g == 0) {
#pragma unroll
        for (int k = 0; k < 4; ++k) {
          pa[k] = xp[(size_t)k * 8192];
          pb[k] = xp[(size_t)k * 8192 + 1];
        }
      }
#pragma unroll 1
      for (int io = 0; io < 8; ++io) {
#pragma unroll
        for (int k = 0; k < 4; ++k) {
          const int t = g * 32 + io * 4 + k;
          const int c = t & 1, p = c ^ 1;
          f32x4 acc[4];
          {
            half8 xlo = __builtin_bit_cast(half8, pa[k]);
            half8 xhi = __builtin_bit_cast(half8, pb[k]);
            acc[0] = (f32x4){(float)xlo[0], (float)xlo[1], (float)xlo[2], (float)xlo[3]};
            acc[1] = (f32x4){(float)xlo[4], (float)xlo[5], (float)xlo[6], (float)xlo[7]};
            acc[2] = (f32x4){(float)xhi[0], (float)xhi[1], (float)xhi[2], (float)xhi[3]};
            acc[3] = (f32x4){(float)xhi[4], (float)xhi[5], (float)xhi[6], (float)xhi[7]};
          }
          half8 B0[4];
#pragma unroll
          for (int s = 0; s < 4; ++s)
            B0[s] = *(const half8*)&sm.rc.h[p][n * 136 + s * 32 + q * 8];
#pragma unroll
          for (int s = 0; s < 4; ++s)
#pragma unroll
            for (int tl = 0; tl < 4; ++tl)
              acc[tl] = __builtin_amdgcn_mfma_f32_16x16x32_f16(WA0[tl][s], B0[s], acc[tl], 0, 0, 0);

          {
            int tn = t + 4; if (tn > T_ - 1) tn = T_ - 1;
            const size_t so = (size_t)(tn & rmask) * 8192;
            pa[k] = xp[so];
            pb[k] = xp[so + 1];
          }

          float h0v[4];
          lstm_cell(acc, c0v, h0v);
          uint2 h0p;
          h0p.x = packh2f(h0v[0], h0v[1]);
          h0p.y = packh2f(h0v[2], h0v[3]);
          *(uint2*)&sm.rc.h[c][hoff] = h0p;
          hg[(size_t)t * 4096] = h0p;

          if (k == 3) {
            vmdrain();   // h0g stores (t-3..t) globally visible before publish
            softbar();
            if (tid == 0)
              __hip_atomic_store(&l0p[b16 * 16], t + 1, __ATOMIC_RELEASE,
                                 __HIP_MEMORY_SCOPE_AGENT);
          } else {
            softbar();   // LDS-only barrier: prefetches stay in flight
          }
        }
      }
      if (tid == 0)
        __hip_atomic_store(&l0c[b16 * 16], g * 32 + 32, __ATOMIC_RELAXED,
                           __HIP_MEMORY_SCOPE_AGENT);
    }
  } else if (bid < 16) {
    // ---------------- Z1: z1(t) = b1 + Wih1 . h0(t) ----------------
    const int b16 = bid - 8;
    half8 WI[4][4];
#pragma unroll
    for (int tl = 0; tl < 4; ++tl)
#pragma unroll
      for (int s = 0; s < 4; ++s)
        WI[tl][s] = __builtin_bit_cast(half8, Wih1f[((w * 4 + tl) * 4 + s) * 64 + L]);
    f32x4 b1v[4];
#pragma unroll
    for (int tl = 0; tl < 4; ++tl) b1v[tl] = b1fD[(w * 64 + L) * 4 + tl];

    const int n2 = tid >> 5, jq = tid & 31;
    const uint2* hsrc = h0g + ((b16 * 16 + n2) * 32 + jq);
    uint4* zdst = z1f + (((size_t)b16 * 8 + w) * 64 + L) * 2;
    const int R2 = rmask2 + 1;
    uint2 hpf[4];

#pragma unroll 1
    for (int p0 = 0; p0 < T_; p0 += 4) {
      if (tid == 0) {
        while (__hip_atomic_load(&l0p[b16 * 16], __ATOMIC_ACQUIRE,
                                 __HIP_MEMORY_SCOPE_AGENT) < p0 + 4)
          __builtin_amdgcn_s_sleep(1);
        if (p0 + 4 > R2) {
          const int need = p0 + 12 - R2;  // z1-ring WAR margin
          while (__hip_atomic_load(&l1p[b16 * 16], __ATOMIC_RELAXED,
                                   __HIP_MEMORY_SCOPE_AGENT) < need)
            __builtin_amdgcn_s_sleep(8);
        }
      }
      __syncthreads();
#pragma unroll
      for (int k = 0; k < 4; ++k) hpf[k] = hsrc[(size_t)(p0 + k) * 4096];
#pragma unroll
      for (int k = 0; k < 4; ++k) {
        const int t = p0 + k;
        const int c = t & 1;
        *(uint2*)&sm.rc.h[c][n2 * 136 + jq * 4] = hpf[k];
        softbar();
        half8 B[4];
#pragma unroll
        for (int s = 0; s < 4; ++s)
          B[s] = *(const half8*)&sm.rc.h[c][n * 136 + s * 32 + q * 8];
        f32x4 acc[4];
#pragma unroll
        for (int tl = 0; tl < 4; ++tl) acc[tl] = b1v[tl];
#pragma unroll
        for (int s = 0; s < 4; ++s)
#pragma unroll
          for (int tl = 0; tl < 4; ++tl)
            acc[tl] = __builtin_amdgcn_mfma_f32_16x16x32_f16(WI[tl][s], B[s], acc[tl], 0, 0, 0);
        uint4 o0, o1;
        o0.x = packh2f(acc[0][0], acc[0][1]); o0.y = packh2f(acc[0][2], acc[0][3]);
        o0.z = packh2f(acc[1][0], acc[1][1]); o0.w = packh2f(acc[1][2], acc[1][3]);
        o1.x = packh2f(acc[2][0], acc[2][1]); o1.y = packh2f(acc[2][2], acc[2][3]);
        o1.z = packh2f(acc[3][0], acc[3][1]); o1.w = packh2f(acc[3][2], acc[3][3]);
        const size_t zs = (size_t)(t & rmask2) * 8192;
        zdst[zs] = o0;
        zdst[zs + 1] = o1;
        softbar();   // protect LDS h[c] WAR for next k (same-parity reuse 2 away)
      }
      vmdrain();     // z1 stores visible before publish
      softbar();
      if (tid == 0)
        __hip_atomic_store(&z1p[b16 * 16], p0 + 4, __ATOMIC_RELEASE,
                           __HIP_MEMORY_SCOPE_AGENT);
    }
  } else if (bid < 24) {
    // ---------------- L1: layer-1 recurrence (Whh1 only) ----------------
    const int b16 = bid - 16;
    half8 WH[4][4];
#pragma unroll
    for (int tl = 0; tl < 4; ++tl)
#pragma unroll
      for (int s = 0; s < 4; ++s)
        WH[tl][s] = __builtin_bit_cast(half8, Whh1f[((w * 4 + tl) * 4 + s) * 64 + L]);

    f32x4 c1v = {0.f, 0.f, 0.f, 0.f};
    f32x4 pool = {0.f, 0.f, 0.f, 0.f};
    const int hoff = n * 136 + w * 16 + q * 4;
    *(uint2*)&sm.rc.h[1][hoff] = make_uint2(0u, 0u);
    __syncthreads();

    const uint4* zp = z1f + (((size_t)b16 * 8 + w) * 64 + L) * 2;
    uint4 pa[4], pb[4];

#pragma unroll 1
    for (int g4 = 0; g4 < 512; ++g4) {
      const int p0 = g4 * 4;
      if (tid == 0) {
        int tgt = p0 + 8; if (tgt > T_) tgt = T_;
        while (__hip_atomic_load(&z1p[b16 * 16], __ATOMIC_ACQUIRE,
                                 __HIP_MEMORY_SCOPE_AGENT) < tgt)
          __builtin_amdgcn_s_sleep(1);
      }
      __syncthreads();
      if (g4 == 0) {
#pragma unroll
        for (int k = 0; k < 4; ++k) {
          pa[k] = zp[(size_t)k * 8192];
          pb[k] = zp[(size_t)k * 8192 + 1];
        }
      }
#pragma unroll
      for (int k = 0; k < 4; ++k) {
        const int t = p0 + k;
        const int c = t & 1, p = c ^ 1;
        f32x4 acc[4];
        {
          half8 xlo = __builtin_bit_cast(half8, pa[k]);
          half8 xhi = __builtin_bit_cast(half8, pb[k]);
          acc[0] = (f32x4){(float)xlo[0], (float)xlo[1], (float)xlo[2], (float)xlo[3]};
          acc[1] = (f32x4){(float)xlo[4], (float)xlo[5], (float)xlo[6], (float)xlo[7]};
          acc[2] = (f32x4){(float)xhi[0], (float)xhi[1], (float)xhi[2], (float)xhi[3]};
          acc[3] = (f32x4){(float)xhi[4], (float)xhi[5], (float)xhi[6], (float)xhi[7]};
        }
        half8 B1[4];
#pragma unroll
        for (int s = 0; s < 4; ++s)
          B1[s] = *(const half8*)&sm.rc.h[p][n * 136 + s * 32 + q * 8];
#pragma unroll
        for (int s = 0; s < 4; ++s)
#pragma unroll
          for (int tl = 0; tl < 4; ++tl)
            acc[tl] = __builtin_amdgcn_mfma_f32_16x16x32_f16(WH[tl][s], B1[s], acc[tl], 0, 0, 0);

        {
          int tn = t + 4; if (tn > T_ - 1) tn = T_ - 1;
          const size_t so = (size_t)(tn & rmask2) * 8192;
          pa[k] = zp[so];
          pb[k] = zp[so + 1];
        }

        float h1v[4];
        lstm_cell(acc, c1v, h1v);
        pool[0] += h1v[0]; pool[1] += h1v[1];
        pool[2] += h1v[2]; pool[3] += h1v[3];
        uint2 h1p;
        h1p.x = packh2f(h1v[0], h1v[1]);
        h1p.y = packh2f(h1v[2], h1v[3]);
        *(uint2*)&sm.rc.h[c][hoff] = h1p;
        softbar();   // LDS-only: z1 prefetches keep flying
      }
      if ((g4 & 1) && tid == 0)
        __hip_atomic_store(&l1p[b16 * 16], p0 + 4, __ATOMIC_RELEASE,
                           __HIP_MEMORY_SCOPE_AGENT);
    }
    psave[(b16 * 8 + w) * 64 + L] = pool;
  } else {
    // ---------------- conv + x0 projection workers ----------------
    const int wi = bid - 24;
    const int co = tid & 127;
    float cw[48];
#pragma unroll
    for (int i = 0; i < 12; ++i) {
      const float4 v = *(const float4*)(conv_w + co * 48 + i * 4);
      cw[i * 4 + 0] = v.x; cw[i * 4 + 1] = v.y;
      cw[i * 4 + 2] = v.z; cw[i * 4 + 3] = v.w;
    }
    const float cb = conv_b[co];
    half8 WB[4][4];
#pragma unroll
    for (int nt4 = 0; nt4 < 4; ++nt4)
#pragma unroll
      for (int s = 0; s < 4; ++s)
        WB[nt4][s] = __builtin_bit_cast(half8, WB0f[((w * 4 + nt4) * 4 + s) * 64 + L]);
    float b0v[4];
#pragma unroll
    for (int nt4 = 0; nt4 < 4; ++nt4) {
      int gg = (w * 4 + nt4) * 16 + n;
      b0v[nt4] = (b_ih0[gg] + b_hh0[gg]) * (((gg >> 7) == 2) ? L2E2 : L2E);
    }
    const int R = rmask + 1;

    for (int u = wi; u < 8192; u += WCV) {
      const int tile = u >> 7, b = u & 127;
      const int t0c = tile * 32;
      if (t0c + 40 > R) {
        const int need = t0c + 40 - R;
        if (tid == 0)
          while (__hip_atomic_load(&l0c[(b >> 4) * 16], __ATOMIC_RELAXED,
                                   __HIP_MEMORY_SCOPE_AGENT) < need)
            __builtin_amdgcn_s_sleep(8);
      }
      __syncthreads();

      for (int idx = tid; idx < 544; idx += 512) {
        int row = idx >> 4, cc2 = idx & 15;
        int gt = t0c - 1 + row;
        sm.wk.xs[idx] = (gt >= 0 && gt < T_) ? x[((size_t)b * T_ + gt) * C_ + cc2] : 0.f;
      }
      __syncthreads();

#pragma unroll
      for (int pp = 0; pp < 8; ++pp) {
        int r = pp * 4 + (tid >> 7);
        float acc = cb;
#pragma unroll
        for (int c16 = 0; c16 < 16; ++c16)
#pragma unroll
          for (int kk = 0; kk < 3; ++kk)
            acc += sm.wk.xs[(r + kk) * 16 + c16] * cw[c16 * 3 + kk];
        acc = acc >= 0.f ? acc : 0.01f * acc;
        sm.wk.yh[r * 136 + co] = (_Float16)acc;
      }
      __syncthreads();

#pragma unroll
      for (int mt = 0; mt < 2; ++mt) {
        half8 A[4];
#pragma unroll
        for (int s = 0; s < 4; ++s)
          A[s] = *(const half8*)&sm.wk.yh[(mt * 16 + n) * 136 + s * 32 + q * 8];
#pragma unroll
        for (int nt4 = 0; nt4 < 4; ++nt4) {
          f32x4 acc = {b0v[nt4], b0v[nt4], b0v[nt4], b0v[nt4]};
#pragma unroll
          for (int s = 0; s < 4; ++s)
            acc = __builtin_amdgcn_mfma_f32_16x16x32_f16(A[s], WB[nt4][s], acc, 0, 0, 0);
          int tau = w * 4 + nt4;
          int off = (tau & 7) * 64 + (n >> 2) * 16 + (tau >> 3) * 4 + (n & 3);
#pragma unroll
          for (int reg = 0; reg < 4; ++reg)
            sm.wk.x0S[(mt * 16 + q * 4 + reg) * 512 + off] = (_Float16)acc[reg];
        }
      }
      __syncthreads();

      const int bn = b & 15, bb16 = b >> 4;
      const int trb = t0c & rmask;
#pragma unroll
      for (int kk = 0; kk < 2; ++kk) {
        int cc = kk * 512 + tid;
        int r = cc >> 5, wq = cc & 31;
        int w2 = wq >> 2, q2 = wq & 3;
        const uint4* src = (const uint4*)&sm.wk.x0S[r * 512 + wq * 16];
        size_t gidx = ((((size_t)(trb + r) * 8 + bb16) * 8 + w2) * 64 + (bn + 16 * q2)) * 2;
        x0f[gidx] = src[0];
        x0f[gidx + 1] = src[1];
      }
      vmdrain();
      __syncthreads();
      if (tid == 0)
        __hip_atomic_fetch_add(&xready[tile * 8 + bb16], 1, __ATOMIC_RELEASE,
                               __HIP_MEMORY_SCOPE_AGENT);
    }
  }
}

// ---------------------------------------------------------------------------
__global__ __launch_bounds__(128) void final_kernel(
    const f32x4* __restrict__ psave, const float* __restrict__ lin_w,
    const float* __restrict__ lin_b, float* __restrict__ out) {
  int b = threadIdx.x;
  int n = b & 15, b16 = b >> 4;
  float acc = 0.f;
  for (int w = 0; w < 8; ++w)
#pragma unroll
    for (int q = 0; q < 4; ++q) {
      f32x4 v = psave[(b16 * 8 + w) * 64 + n + 16 * q];
#pragma unroll
      for (int reg = 0; reg < 4; ++reg)
        acc += v[reg] * lin_w[w * 16 + q * 4 + reg];
    }
  out[b] = acc * (1.0f / (float)T_) + lin_b[0];
}

// ---------------------------------------------------------------------------
extern "C" void kernel_launch(void* const* d_in, const int* in_sizes, int n_in,
                              void* d_out, int out_size, void* d_ws, size_t ws_size,
                              hipStream_t stream) {
  (void)in_sizes; (void)n_in; (void)out_size;
  const float* x      = (const float*)d_in[0];
  const float* conv_w = (const float*)d_in[1];
  const float* conv_b = (const float*)d_in[2];
  const float* w_ih0  = (const float*)d_in[3];
  const float* w_hh0  = (const float*)d_in[4];
  const float* b_ih0  = (const float*)d_in[5];
  const float* b_hh0  = (const float*)d_in[6];
  const float* w_ih1  = (const float*)d_in[7];
  const float* w_hh1  = (const float*)d_in[8];
  const float* b_ih1  = (const float*)d_in[9];
  const float* b_hh1  = (const float*)d_in[10];
  const float* lin_w  = (const float*)d_in[11];
  const float* lin_b  = (const float*)d_in[12];

  char* ws = (char*)d_ws;
  uint4* Wf0   = (uint4*)(ws + 0);        // 131072
  uint4* Wih1f = (uint4*)(ws + 131072);   // 131072
  uint4* Whh1f = (uint4*)(ws + 262144);   // 131072
  uint4* WB0f  = (uint4*)(ws + 393216);   // 131072
  f32x4* b1fD  = (f32x4*)(ws + 524288);   // 32768
  f32x4* psave = (f32x4*)(ws + 557056);   // 65536
  int*   flags = (int*)(ws + 622592);     // 4096 (1024 ints, line-padded)
  uint2* h0g   = (uint2*)(ws + 626688);   // 67108864 (full-T h0 stream)
  const size_t base = 626688 + 67108864;  // 67735552

  int R = 256, R2 = 256;  // x0 ring, z1 ring (steps)
  while (R > 64 && base + ((size_t)R + (size_t)R2) * 131072 > ws_size) {
    R >>= 1; R2 >>= 1;
  }
  uint4* x0f = (uint4*)(ws + base);
  uint4* z1f = (uint4*)(ws + base + (size_t)R * 131072);

  hipMemsetAsync(flags, 0, 4096, stream);
  pack_kernel<<<136, 256, 0, stream>>>(w_ih0, w_hh0, w_ih1, w_hh1, b_ih1, b_hh1,
                                       Wf0, Wih1f, Whh1f, WB0f, b1fD);
  persist_kernel<<<NBLK, 512, 0, stream>>>(
      x, conv_w, conv_b, b_ih0, b_hh0, Wf0, Wih1f, Whh1f, WB0f, b1fD,
      x0f, h0g, z1f, psave, flags, R - 1, R2 - 1);
  final_kernel<<<1, 128, 0, stream>>>(psave, lin_w, lin_b, (float*)d_out);
}

// Round 12
// 2213.233 us; speedup vs baseline: 1.0147x; 1.0147x over previous
//
#include <hip/hip_runtime.h>
#include <hip/hip_fp16.h>
#include <cstdint>
#include <cstddef>

#define B_ 128
#define T_ 2048
#define C_ 16
#define CO_ 128
#define H_ 128
#define G_ 512
#define WCV 232                 // conv/x0 worker blocks
#define NBLK (24 + WCV)         // 256 = 8 L0 + 8 Z1 + 8 L1 + workers
#define L2E  1.4426950408889634f
#define L2E2 2.8853900817779268f

typedef _Float16 half8 __attribute__((ext_vector_type(8)));
typedef float f32x4 __attribute__((ext_vector_type(4)));

__device__ __forceinline__ unsigned packh2f(float a, float b) {
  union { _Float16 h[2]; unsigned u; } x;
  x.h[0] = (_Float16)a; x.h[1] = (_Float16)b;
  return x.u;
}

__device__ __forceinline__ float rcpf(float x) { return __builtin_amdgcn_rcpf(x); }

__device__ __forceinline__ float exp2f_(float x) {
#if __has_builtin(__builtin_amdgcn_exp2f)
  return __builtin_amdgcn_exp2f(x);
#else
  return __expf(x * 0.6931471805599453f);
#endif
}

// Soft barrier: LDS-visibility only (global prefetches stay in flight).
__device__ __forceinline__ void softbar() {
  asm volatile("s_waitcnt lgkmcnt(0)\n\ts_barrier" ::: "memory");
}
__device__ __forceinline__ void vmdrain() {
  asm volatile("s_waitcnt vmcnt(0)" ::: "memory");
}

// Gates arrive PRE-SCALED: i,f,o by log2e; g by 2*log2e.
__device__ __forceinline__ void lstm_cell(const f32x4* acc, f32x4& c, float* h) {
#pragma unroll
  for (int r = 0; r < 4; ++r) {
    float iv = acc[0][r], fv = acc[1][r], gv = acc[2][r], ov = acc[3][r];
    gv = fminf(fmaxf(gv, -43.3f), 43.3f);
    float ei = exp2f_(-iv), ef = exp2f_(-fv), eg = exp2f_(gv);
    float P = (1.f + ei) * (eg + 1.f);
    float Q = 1.f + ef;
    float num = c[r] * P + (eg - 1.f) * Q;
    float cN = num * rcpf(Q * P);
    c[r] = cN;
    float cc = fminf(fmaxf(cN, -15.f), 15.f);
    float eo = exp2f_(-ov), ec = exp2f_(L2E2 * cc);
    h[r] = (ec - 1.f) * rcpf((1.f + eo) * (ec + 1.f));
  }
}

// ---------------------------------------------------------------------------
// pack_kernel: fragment-ordered weight buffers (pre-scaled by log2e / 2log2e).
// ---------------------------------------------------------------------------
__global__ __launch_bounds__(256) void pack_kernel(
    const float* __restrict__ w_ih0, const float* __restrict__ w_hh0,
    const float* __restrict__ w_ih1, const float* __restrict__ w_hh1,
    const float* __restrict__ b_ih1, const float* __restrict__ b_hh1,
    uint4* __restrict__ Wf0, uint4* __restrict__ Wih1f,
    uint4* __restrict__ Whh1f, uint4* __restrict__ WB0f,
    f32x4* __restrict__ b1fD) {
  int tid = blockIdx.x * 256 + threadIdx.x;
  if (tid < 24576) {
    int u = tid & 8191, L = u & 63, s = (u >> 6) & 3, tl = (u >> 8) & 3, w = u >> 10;
    int which = tid >> 13;
    const float* src = (which == 0) ? w_hh0 : (which == 1) ? w_ih1 : w_hh1;
    uint4* dst = (which == 0) ? Wf0 : (which == 1) ? Wih1f : Whh1f;
    int m = (w + 8 * tl) * 16 + (L & 15);
    float sc = (tl == 2) ? L2E2 : L2E;
    int k0 = s * 32 + (L >> 4) * 8;
    const float* p = src + m * 128 + k0;
    uint4 o;
    o.x = packh2f(p[0] * sc, p[1] * sc); o.y = packh2f(p[2] * sc, p[3] * sc);
    o.z = packh2f(p[4] * sc, p[5] * sc); o.w = packh2f(p[6] * sc, p[7] * sc);
    dst[u] = o;
  } else if (tid < 32768) {
    int u = tid - 24576, L = u & 63, s = (u >> 6) & 3, nt = u >> 8;
    int g = nt * 16 + (L & 15);
    float sc = ((nt >> 3) == 2) ? L2E2 : L2E;
    int k0 = s * 32 + (L >> 4) * 8;
    const float* p = w_ih0 + g * 128 + k0;
    uint4 o;
    o.x = packh2f(p[0] * sc, p[1] * sc); o.y = packh2f(p[2] * sc, p[3] * sc);
    o.z = packh2f(p[4] * sc, p[5] * sc); o.w = packh2f(p[6] * sc, p[7] * sc);
    WB0f[u] = o;
  } else if (tid < 34816) {
    int u2 = tid - 32768;
    int tl = u2 & 3, L = (u2 >> 2) & 63, w = u2 >> 8;
    int q = L >> 4;
    float sc = (tl == 2) ? L2E2 : L2E;
    f32x4 o;
#pragma unroll
    for (int reg = 0; reg < 4; ++reg) {
      int row = (w + 8 * tl) * 16 + q * 4 + reg;
      o[reg] = (b_ih1[row] + b_hh1[row]) * sc;
    }
    b1fD[u2] = o;
  }
}

// ---------------------------------------------------------------------------
// persist_kernel — R10 structure + FULL-T x0 buffer:
//  bid 0..7  : L0  (Whh0 + cell0; h0 -> LDS + h0g; publishes l0p /4 steps)
//  bid 8..15 : Z1  (z1 = b1 + Wih1.h0 from h0g, 4-step windows -> z1f ring)
//  bid 16..23: L1  (Whh1 + cell1 + pool; consumes z1f ring)
//  bid 24..  : workers sprint through ALL 2048 x0 tiles then RETIRE,
//              quiescing their CUs (power/clock headroom for role CUs).
// Soft barriers keep the 4-deep prefetch in flight (covers cold-HBM x0).
// ---------------------------------------------------------------------------
__global__ __launch_bounds__(512, 2) void persist_kernel(
    const float* __restrict__ x, const float* __restrict__ conv_w,
    const float* __restrict__ conv_b, const float* __restrict__ b_ih0,
    const float* __restrict__ b_hh0,
    const uint4* __restrict__ Wf0, const uint4* __restrict__ Wih1f,
    const uint4* __restrict__ Whh1f, const uint4* __restrict__ WB0f,
    const f32x4* __restrict__ b1fD,
    uint4* __restrict__ x0f, uint2* __restrict__ h0g, uint4* __restrict__ z1f,
    f32x4* __restrict__ psave, int* __restrict__ flags,
    int rmask, int rmask2) {
  __shared__ __align__(16) union {
    struct { float xs[34 * 16]; _Float16 yh[32 * 136]; _Float16 x0S[32 * 512]; } wk;
    struct { _Float16 h[2][16 * 136]; } rc;
  } sm;

  int* xready = flags;          // [tile*8 + b16], 512 ints
  int* l0p = flags + 512;       // + b16*16
  int* l0c = flags + 640;       // + b16*16
  int* z1p = flags + 768;       // + b16*16
  int* l1p = flags + 896;       // + b16*16

  const int bid = blockIdx.x;
  const int tid = threadIdx.x;
  const int w = tid >> 6, L = tid & 63, q = L >> 4, n = L & 15;

  if (bid < 8) {
    // ---------------- L0: layer-0 recurrence ----------------
    const int b16 = bid;
    half8 WA0[4][4];
#pragma unroll
    for (int tl = 0; tl < 4; ++tl)
#pragma unroll
      for (int s = 0; s < 4; ++s)
        WA0[tl][s] = __builtin_bit_cast(half8, Wf0[((w * 4 + tl) * 4 + s) * 64 + L]);

    f32x4 c0v = {0.f, 0.f, 0.f, 0.f};
    const int hoff = n * 136 + w * 16 + q * 4;
    *(uint2*)&sm.rc.h[1][hoff] = make_uint2(0u, 0u);
    __syncthreads();

    const uint4* xp = x0f + (((size_t)b16 * 8 + w) * 64 + L) * 2;
    uint2* hg = h0g + ((b16 * 16 + n) * 32 + w * 4 + q);
    uint4 pa[4], pb[4];

    for (int g = 0; g < 64; ++g) {
      if (tid == 0) {
        while (__hip_atomic_load(&xready[g * 8 + b16], __ATOMIC_ACQUIRE,
                                 __HIP_MEMORY_SCOPE_AGENT) < 16)
          __builtin_amdgcn_s_sleep(2);
        if (g < 63)
          while (__hip_atomic_load(&xready[(g + 1) * 8 + b16], __ATOMIC_ACQUIRE,
                                   __HIP_MEMORY_SCOPE_AGENT) < 16)
            __builtin_amdgcn_s_sleep(2);
      }
      __syncthreads();
      if (g == 0) {
#pragma unroll
        for (int k = 0; k < 4; ++k) {
          pa[k] = xp[(size_t)k * 8192];
          pb[k] = xp[(size_t)k * 8192 + 1];
        }
      }
#pragma unroll 1
      for (int io = 0; io < 8; ++io) {
#pragma unroll
        for (int k = 0; k < 4; ++k) {
          const int t = g * 32 + io * 4 + k;
          const int c = t & 1, p = c ^ 1;
          f32x4 acc[4];
          {
            half8 xlo = __builtin_bit_cast(half8, pa[k]);
            half8 xhi = __builtin_bit_cast(half8, pb[k]);
            acc[0] = (f32x4){(float)xlo[0], (float)xlo[1], (float)xlo[2], (float)xlo[3]};
            acc[1] = (f32x4){(float)xlo[4], (float)xlo[5], (float)xlo[6], (float)xlo[7]};
            acc[2] = (f32x4){(float)xhi[0], (float)xhi[1], (float)xhi[2], (float)xhi[3]};
            acc[3] = (f32x4){(float)xhi[4], (float)xhi[5], (float)xhi[6], (float)xhi[7]};
          }
          half8 B0[4];
#pragma unroll
          for (int s = 0; s < 4; ++s)
            B0[s] = *(const half8*)&sm.rc.h[p][n * 136 + s * 32 + q * 8];
#pragma unroll
          for (int s = 0; s < 4; ++s)
#pragma unroll
            for (int tl = 0; tl < 4; ++tl)
              acc[tl] = __builtin_amdgcn_mfma_f32_16x16x32_f16(WA0[tl][s], B0[s], acc[tl], 0, 0, 0);

          {
            int tn = t + 4; if (tn > T_ - 1) tn = T_ - 1;
            const size_t so = (size_t)(tn & rmask) * 8192;
            pa[k] = xp[so];
            pb[k] = xp[so + 1];
          }

          float h0v[4];
          lstm_cell(acc, c0v, h0v);
          uint2 h0p;
          h0p.x = packh2f(h0v[0], h0v[1]);
          h0p.y = packh2f(h0v[2], h0v[3]);
          *(uint2*)&sm.rc.h[c][hoff] = h0p;
          hg[(size_t)t * 4096] = h0p;

          if (k == 3) {
            vmdrain();   // h0g stores (t-3..t) globally visible before publish
            softbar();
            if (tid == 0)
              __hip_atomic_store(&l0p[b16 * 16], t + 1, __ATOMIC_RELEASE,
                                 __HIP_MEMORY_SCOPE_AGENT);
          } else {
            softbar();   // LDS-only barrier: prefetches stay in flight
          }
        }
      }
      if (tid == 0)
        __hip_atomic_store(&l0c[b16 * 16], g * 32 + 32, __ATOMIC_RELAXED,
                           __HIP_MEMORY_SCOPE_AGENT);
    }
  } else if (bid < 16) {
    // ---------------- Z1: z1(t) = b1 + Wih1 . h0(t) ----------------
    const int b16 = bid - 8;
    half8 WI[4][4];
#pragma unroll
    for (int tl = 0; tl < 4; ++tl)
#pragma unroll
      for (int s = 0; s < 4; ++s)
        WI[tl][s] = __builtin_bit_cast(half8, Wih1f[((w * 4 + tl) * 4 + s) * 64 + L]);
    f32x4 b1v[4];
#pragma unroll
    for (int tl = 0; tl < 4; ++tl) b1v[tl] = b1fD[(w * 64 + L) * 4 + tl];

    const int n2 = tid >> 5, jq = tid & 31;
    const uint2* hsrc = h0g + ((b16 * 16 + n2) * 32 + jq);
    uint4* zdst = z1f + (((size_t)b16 * 8 + w) * 64 + L) * 2;
    const int R2 = rmask2 + 1;
    uint2 hpf[4];

#pragma unroll 1
    for (int p0 = 0; p0 < T_; p0 += 4) {
      if (tid == 0) {
        while (__hip_atomic_load(&l0p[b16 * 16], __ATOMIC_ACQUIRE,
                                 __HIP_MEMORY_SCOPE_AGENT) < p0 + 4)
          __builtin_amdgcn_s_sleep(1);
        if (p0 + 4 > R2) {
          const int need = p0 + 12 - R2;  // z1-ring WAR margin
          while (__hip_atomic_load(&l1p[b16 * 16], __ATOMIC_RELAXED,
                                   __HIP_MEMORY_SCOPE_AGENT) < need)
            __builtin_amdgcn_s_sleep(8);
        }
      }
      __syncthreads();
#pragma unroll
      for (int k = 0; k < 4; ++k) hpf[k] = hsrc[(size_t)(p0 + k) * 4096];
#pragma unroll
      for (int k = 0; k < 4; ++k) {
        const int t = p0 + k;
        const int c = t & 1;
        *(uint2*)&sm.rc.h[c][n2 * 136 + jq * 4] = hpf[k];
        softbar();
        half8 B[4];
#pragma unroll
        for (int s = 0; s < 4; ++s)
          B[s] = *(const half8*)&sm.rc.h[c][n * 136 + s * 32 + q * 8];
        f32x4 acc[4];
#pragma unroll
        for (int tl = 0; tl < 4; ++tl) acc[tl] = b1v[tl];
#pragma unroll
        for (int s = 0; s < 4; ++s)
#pragma unroll
          for (int tl = 0; tl < 4; ++tl)
            acc[tl] = __builtin_amdgcn_mfma_f32_16x16x32_f16(WI[tl][s], B[s], acc[tl], 0, 0, 0);
        uint4 o0, o1;
        o0.x = packh2f(acc[0][0], acc[0][1]); o0.y = packh2f(acc[0][2], acc[0][3]);
        o0.z = packh2f(acc[1][0], acc[1][1]); o0.w = packh2f(acc[1][2], acc[1][3]);
        o1.x = packh2f(acc[2][0], acc[2][1]); o1.y = packh2f(acc[2][2], acc[2][3]);
        o1.z = packh2f(acc[3][0], acc[3][1]); o1.w = packh2f(acc[3][2], acc[3][3]);
        const size_t zs = (size_t)(t & rmask2) * 8192;
        zdst[zs] = o0;
        zdst[zs + 1] = o1;
        softbar();   // protect LDS h[c] WAR for next k (same-parity reuse 2 away)
      }
      vmdrain();     // z1 stores visible before publish
      softbar();
      if (tid == 0)
        __hip_atomic_store(&z1p[b16 * 16], p0 + 4, __ATOMIC_RELEASE,
                           __HIP_MEMORY_SCOPE_AGENT);
    }
  } else if (bid < 24) {
    // ---------------- L1: layer-1 recurrence (Whh1 only) ----------------
    const int b16 = bid - 16;
    half8 WH[4][4];
#pragma unroll
    for (int tl = 0; tl < 4; ++tl)
#pragma unroll
      for (int s = 0; s < 4; ++s)
        WH[tl][s] = __builtin_bit_cast(half8, Whh1f[((w * 4 + tl) * 4 + s) * 64 + L]);

    f32x4 c1v = {0.f, 0.f, 0.f, 0.f};
    f32x4 pool = {0.f, 0.f, 0.f, 0.f};
    const int hoff = n * 136 + w * 16 + q * 4;
    *(uint2*)&sm.rc.h[1][hoff] = make_uint2(0u, 0u);
    __syncthreads();

    const uint4* zp = z1f + (((size_t)b16 * 8 + w) * 64 + L) * 2;
    uint4 pa[4], pb[4];

#pragma unroll 1
    for (int g4 = 0; g4 < 512; ++g4) {
      const int p0 = g4 * 4;
      if (tid == 0) {
        int tgt = p0 + 8; if (tgt > T_) tgt = T_;
        while (__hip_atomic_load(&z1p[b16 * 16], __ATOMIC_ACQUIRE,
                                 __HIP_MEMORY_SCOPE_AGENT) < tgt)
          __builtin_amdgcn_s_sleep(1);
      }
      __syncthreads();
      if (g4 == 0) {
#pragma unroll
        for (int k = 0; k < 4; ++k) {
          pa[k] = zp[(size_t)k * 8192];
          pb[k] = zp[(size_t)k * 8192 + 1];
        }
      }
#pragma unroll
      for (int k = 0; k < 4; ++k) {
        const int t = p0 + k;
        const int c = t & 1, p = c ^ 1;
        f32x4 acc[4];
        {
          half8 xlo = __builtin_bit_cast(half8, pa[k]);
          half8 xhi = __builtin_bit_cast(half8, pb[k]);
          acc[0] = (f32x4){(float)xlo[0], (float)xlo[1], (float)xlo[2], (float)xlo[3]};
          acc[1] = (f32x4){(float)xlo[4], (float)xlo[5], (float)xlo[6], (float)xlo[7]};
          acc[2] = (f32x4){(float)xhi[0], (float)xhi[1], (float)xhi[2], (float)xhi[3]};
          acc[3] = (f32x4){(float)xhi[4], (float)xhi[5], (float)xhi[6], (float)xhi[7]};
        }
        half8 B1[4];
#pragma unroll
        for (int s = 0; s < 4; ++s)
          B1[s] = *(const half8*)&sm.rc.h[p][n * 136 + s * 32 + q * 8];
#pragma unroll
        for (int s = 0; s < 4; ++s)
#pragma unroll
          for (int tl = 0; tl < 4; ++tl)
            acc[tl] = __builtin_amdgcn_mfma_f32_16x16x32_f16(WH[tl][s], B1[s], acc[tl], 0, 0, 0);

        {
          int tn = t + 4; if (tn > T_ - 1) tn = T_ - 1;
          const size_t so = (size_t)(tn & rmask2) * 8192;
          pa[k] = zp[so];
          pb[k] = zp[so + 1];
        }

        float h1v[4];
        lstm_cell(acc, c1v, h1v);
        pool[0] += h1v[0]; pool[1] += h1v[1];
        pool[2] += h1v[2]; pool[3] += h1v[3];
        uint2 h1p;
        h1p.x = packh2f(h1v[0], h1v[1]);
        h1p.y = packh2f(h1v[2], h1v[3]);
        *(uint2*)&sm.rc.h[c][hoff] = h1p;
        softbar();   // LDS-only: z1 prefetches keep flying
      }
      if ((g4 & 1) && tid == 0)
        __hip_atomic_store(&l1p[b16 * 16], p0 + 4, __ATOMIC_RELEASE,
                           __HIP_MEMORY_SCOPE_AGENT);
    }
    psave[(b16 * 8 + w) * 64 + L] = pool;
  } else {
    // ---------------- conv + x0 projection workers (sprint, then retire) ----
    const int wi = bid - 24;
    const int co = tid & 127;
    float cw[48];
#pragma unroll
    for (int i = 0; i < 12; ++i) {
      const float4 v = *(const float4*)(conv_w + co * 48 + i * 4);
      cw[i * 4 + 0] = v.x; cw[i * 4 + 1] = v.y;
      cw[i * 4 + 2] = v.z; cw[i * 4 + 3] = v.w;
    }
    const float cb = conv_b[co];
    half8 WB[4][4];
#pragma unroll
    for (int nt4 = 0; nt4 < 4; ++nt4)
#pragma unroll
      for (int s = 0; s < 4; ++s)
        WB[nt4][s] = __builtin_bit_cast(half8, WB0f[((w * 4 + nt4) * 4 + s) * 64 + L]);
    float b0v[4];
#pragma unroll
    for (int nt4 = 0; nt4 < 4; ++nt4) {
      int gg = (w * 4 + nt4) * 16 + n;
      b0v[nt4] = (b_ih0[gg] + b_hh0[gg]) * (((gg >> 7) == 2) ? L2E2 : L2E);
    }
    const int R = rmask + 1;

    for (int u = wi; u < 8192; u += WCV) {
      const int tile = u >> 7, b = u & 127;
      const int t0c = tile * 32;
      if (t0c + 40 > R) {
        const int need = t0c + 40 - R;
        if (tid == 0)
          while (__hip_atomic_load(&l0c[(b >> 4) * 16], __ATOMIC_RELAXED,
                                   __HIP_MEMORY_SCOPE_AGENT) < need)
            __builtin_amdgcn_s_sleep(8);
      }
      __syncthreads();

      for (int idx = tid; idx < 544; idx += 512) {
        int row = idx >> 4, cc2 = idx & 15;
        int gt = t0c - 1 + row;
        sm.wk.xs[idx] = (gt >= 0 && gt < T_) ? x[((size_t)b * T_ + gt) * C_ + cc2] : 0.f;
      }
      __syncthreads();

#pragma unroll
      for (int pp = 0; pp < 8; ++pp) {
        int r = pp * 4 + (tid >> 7);
        float acc = cb;
#pragma unroll
        for (int c16 = 0; c16 < 16; ++c16)
#pragma unroll
          for (int kk = 0; kk < 3; ++kk)
            acc += sm.wk.xs[(r + kk) * 16 + c16] * cw[c16 * 3 + kk];
        acc = acc >= 0.f ? acc : 0.01f * acc;
        sm.wk.yh[r * 136 + co] = (_Float16)acc;
      }
      __syncthreads();

#pragma unroll
      for (int mt = 0; mt < 2; ++mt) {
        half8 A[4];
#pragma unroll
        for (int s = 0; s < 4; ++s)
          A[s] = *(const half8*)&sm.wk.yh[(mt * 16 + n) * 136 + s * 32 + q * 8];
#pragma unroll
        for (int nt4 = 0; nt4 < 4; ++nt4) {
          f32x4 acc = {b0v[nt4], b0v[nt4], b0v[nt4], b0v[nt4]};
#pragma unroll
          for (int s = 0; s < 4; ++s)
            acc = __builtin_amdgcn_mfma_f32_16x16x32_f16(A[s], WB[nt4][s], acc, 0, 0, 0);
          int tau = w * 4 + nt4;
          int off = (tau & 7) * 64 + (n >> 2) * 16 + (tau >> 3) * 4 + (n & 3);
#pragma unroll
          for (int reg = 0; reg < 4; ++reg)
            sm.wk.x0S[(mt * 16 + q * 4 + reg) * 512 + off] = (_Float16)acc[reg];
        }
      }
      __syncthreads();

      const int bn = b & 15, bb16 = b >> 4;
      const int trb = t0c & rmask;
#pragma unroll
      for (int kk = 0; kk < 2; ++kk) {
        int cc = kk * 512 + tid;
        int r = cc >> 5, wq = cc & 31;
        int w2 = wq >> 2, q2 = wq & 3;
        const uint4* src = (const uint4*)&sm.wk.x0S[r * 512 + wq * 16];
        size_t gidx = ((((size_t)(trb + r) * 8 + bb16) * 8 + w2) * 64 + (bn + 16 * q2)) * 2;
        x0f[gidx] = src[0];
        x0f[gidx + 1] = src[1];
      }
      vmdrain();
      __syncthreads();
      if (tid == 0)
        __hip_atomic_fetch_add(&xready[tile * 8 + bb16], 1, __ATOMIC_RELEASE,
                               __HIP_MEMORY_SCOPE_AGENT);
    }
  }
}

// ---------------------------------------------------------------------------
__global__ __launch_bounds__(128) void final_kernel(
    const f32x4* __restrict__ psave, const float* __restrict__ lin_w,
    const float* __restrict__ lin_b, float* __restrict__ out) {
  int b = threadIdx.x;
  int n = b & 15, b16 = b >> 4;
  float acc = 0.f;
  for (int w = 0; w < 8; ++w)
#pragma unroll
    for (int q = 0; q < 4; ++q) {
      f32x4 v = psave[(b16 * 8 + w) * 64 + n + 16 * q];
#pragma unroll
      for (int reg = 0; reg < 4; ++reg)
        acc += v[reg] * lin_w[w * 16 + q * 4 + reg];
    }
  out[b] = acc * (1.0f / (float)T_) + lin_b[0];
}

// ---------------------------------------------------------------------------
extern "C" void kernel_launch(void* const* d_in, const int* in_sizes, int n_in,
                              void* d_out, int out_size, void* d_ws, size_t ws_size,
                              hipStream_t stream) {
  (void)in_sizes; (void)n_in; (void)out_size;
  const float* x      = (const float*)d_in[0];
  const float* conv_w = (const float*)d_in[1];
  const float* conv_b = (const float*)d_in[2];
  const float* w_ih0  = (const float*)d_in[3];
  const float* w_hh0  = (const float*)d_in[4];
  const float* b_ih0  = (const float*)d_in[5];
  const float* b_hh0  = (const float*)d_in[6];
  const float* w_ih1  = (const float*)d_in[7];
  const float* w_hh1  = (const float*)d_in[8];
  const float* b_ih1  = (const float*)d_in[9];
  const float* b_hh1  = (const float*)d_in[10];
  const float* lin_w  = (const float*)d_in[11];
  const float* lin_b  = (const float*)d_in[12];

  char* ws = (char*)d_ws;
  uint4* Wf0   = (uint4*)(ws + 0);        // 131072
  uint4* Wih1f = (uint4*)(ws + 131072);   // 131072
  uint4* Whh1f = (uint4*)(ws + 262144);   // 131072
  uint4* WB0f  = (uint4*)(ws + 393216);   // 131072
  f32x4* b1fD  = (f32x4*)(ws + 524288);   // 32768
  f32x4* psave = (f32x4*)(ws + 557056);   // 65536
  int*   flags = (int*)(ws + 622592);     // 4096 (1024 ints, line-padded)
  uint2* h0g   = (uint2*)(ws + 626688);   // 67108864 (full-T h0 stream)
  const size_t base = 626688 + 67108864;  // 67735552

  // x0: FULL T preferred (workers sprint then retire -> quiesce 232 CUs);
  // fall back to a ring only if ws is too small. z1 stays a warm 256-step ring.
  int R = 2048, R2 = 256;
  while (R > 256 && base + ((size_t)R + (size_t)R2) * 131072 > ws_size) R >>= 1;
  while (R > 64 && base + ((size_t)R + (size_t)R2) * 131072 > ws_size) R >>= 1;
  while (R2 > 64 && base + ((size_t)R + (size_t)R2) * 131072 > ws_size) R2 >>= 1;
  uint4* x0f = (uint4*)(ws + base);
  uint4* z1f = (uint4*)(ws + base + (size_t)R * 131072);

  hipMemsetAsync(flags, 0, 4096, stream);
  pack_kernel<<<136, 256, 0, stream>>>(w_ih0, w_hh0, w_ih1, w_hh1, b_ih1, b_hh1,
                                       Wf0, Wih1f, Whh1f, WB0f, b1fD);
  persist_kernel<<<NBLK, 512, 0, stream>>>(
      x, conv_w, conv_b, b_ih0, b_hh0, Wf0, Wih1f, Whh1f, WB0f, b1fD,
      x0f, h0g, z1f, psave, flags, R - 1, R2 - 1);
  final_kernel<<<1, 128, 0, stream>>>(psave, lin_w, lin_b, (float*)d_out);
}

// Round 13
// 2116.021 us; speedup vs baseline: 1.0614x; 1.0459x over previous
//
#include <hip/hip_runtime.h>
#include <hip/hip_fp16.h>
#include <cstdint>
#include <cstddef>

#define B_ 128
#define T_ 2048
#define C_ 16
#define CO_ 128
#define H_ 128
#define G_ 512
#define WCV 232                 // conv/x0 worker blocks
#define NBLK (24 + WCV)         // 256 = 8 L0 + 8 Z1 + 8 L1 + workers
#define L2E  1.4426950408889634f
#define L2E2 2.8853900817779268f

typedef _Float16 half8 __attribute__((ext_vector_type(8)));
typedef float f32x4 __attribute__((ext_vector_type(4)));

__device__ __forceinline__ unsigned packh2f(float a, float b) {
  union { _Float16 h[2]; unsigned u; } x;
  x.h[0] = (_Float16)a; x.h[1] = (_Float16)b;
  return x.u;
}

__device__ __forceinline__ float rcpf(float x) { return __builtin_amdgcn_rcpf(x); }

__device__ __forceinline__ float exp2f_(float x) {
#if __has_builtin(__builtin_amdgcn_exp2f)
  return __builtin_amdgcn_exp2f(x);
#else
  return __expf(x * 0.6931471805599453f);
#endif
}

__device__ __forceinline__ void vmdrain() {
  asm volatile("s_waitcnt vmcnt(0)" ::: "memory");
}

// Gates arrive PRE-SCALED: i,f,o by log2e; g by 2*log2e.
__device__ __forceinline__ void lstm_cell(const f32x4* acc, f32x4& c, float* h) {
#pragma unroll
  for (int r = 0; r < 4; ++r) {
    float iv = acc[0][r], fv = acc[1][r], gv = acc[2][r], ov = acc[3][r];
    gv = fminf(fmaxf(gv, -43.3f), 43.3f);
    float ei = exp2f_(-iv), ef = exp2f_(-fv), eg = exp2f_(gv);
    float P = (1.f + ei) * (eg + 1.f);
    float Q = 1.f + ef;
    float num = c[r] * P + (eg - 1.f) * Q;
    float cN = num * rcpf(Q * P);
    c[r] = cN;
    float cc = fminf(fmaxf(cN, -15.f), 15.f);
    float eo = exp2f_(-ov), ec = exp2f_(L2E2 * cc);
    h[r] = (ec - 1.f) * rcpf((1.f + eo) * (ec + 1.f));
  }
}

// h LDS layout: [s(4)][q(4)][n(16)][8 halfs]  (2048 halfs / 4 KB per buffer).
// B-frag read for lane (q,n): &h[((s*4+q)*16+n)*8] -> lane-linear 16B,
// stride-1 across lanes => conflict-free b128 (old [n][j] stride-136 layout
// had 8-way conflicts: bank = 68n+16s+4q mod 32, multiples of 4 only --
// matches the measured 1.47e7 SQ_LDS_BANK_CONFLICT).
// Cell writer (gate j = w*16+q*4+r, batch n) lands 4 contiguous halfs at:
//   ((s*4 + q_r)*16 + n)*8 + (q&1)*4,  s = w>>1, q_r = 2*(w&1) + (q>>1).
__device__ __forceinline__ int h_write_off(int w, int q, int n) {
  int s = w >> 1;
  int qr = 2 * (w & 1) + (q >> 1);
  return ((s * 4 + qr) * 16 + n) * 8 + (q & 1) * 4;
}

// ---------------------------------------------------------------------------
// pack_kernel: fragment-ordered weight buffers (pre-scaled by log2e / 2log2e).
// ---------------------------------------------------------------------------
__global__ __launch_bounds__(256) void pack_kernel(
    const float* __restrict__ w_ih0, const float* __restrict__ w_hh0,
    const float* __restrict__ w_ih1, const float* __restrict__ w_hh1,
    const float* __restrict__ b_ih1, const float* __restrict__ b_hh1,
    uint4* __restrict__ Wf0, uint4* __restrict__ Wih1f,
    uint4* __restrict__ Whh1f, uint4* __restrict__ WB0f,
    f32x4* __restrict__ b1fD) {
  int tid = blockIdx.x * 256 + threadIdx.x;
  if (tid < 24576) {
    int u = tid & 8191, L = u & 63, s = (u >> 6) & 3, tl = (u >> 8) & 3, w = u >> 10;
    int which = tid >> 13;
    const float* src = (which == 0) ? w_hh0 : (which == 1) ? w_ih1 : w_hh1;
    uint4* dst = (which == 0) ? Wf0 : (which == 1) ? Wih1f : Whh1f;
    int m = (w + 8 * tl) * 16 + (L & 15);
    float sc = (tl == 2) ? L2E2 : L2E;
    int k0 = s * 32 + (L >> 4) * 8;
    const float* p = src + m * 128 + k0;
    uint4 o;
    o.x = packh2f(p[0] * sc, p[1] * sc); o.y = packh2f(p[2] * sc, p[3] * sc);
    o.z = packh2f(p[4] * sc, p[5] * sc); o.w = packh2f(p[6] * sc, p[7] * sc);
    dst[u] = o;
  } else if (tid < 32768) {
    int u = tid - 24576, L = u & 63, s = (u >> 6) & 3, nt = u >> 8;
    int g = nt * 16 + (L & 15);
    float sc = ((nt >> 3) == 2) ? L2E2 : L2E;
    int k0 = s * 32 + (L >> 4) * 8;
    const float* p = w_ih0 + g * 128 + k0;
    uint4 o;
    o.x = packh2f(p[0] * sc, p[1] * sc); o.y = packh2f(p[2] * sc, p[3] * sc);
    o.z = packh2f(p[4] * sc, p[5] * sc); o.w = packh2f(p[6] * sc, p[7] * sc);
    WB0f[u] = o;
  } else if (tid < 34816) {
    int u2 = tid - 32768;
    int tl = u2 & 3, L = (u2 >> 2) & 63, w = u2 >> 8;
    int q = L >> 4;
    float sc = (tl == 2) ? L2E2 : L2E;
    f32x4 o;
#pragma unroll
    for (int reg = 0; reg < 4; ++reg) {
      int row = (w + 8 * tl) * 16 + q * 4 + reg;
      o[reg] = (b_ih1[row] + b_hh1[row]) * sc;
    }
    b1fD[u2] = o;
  }
}

// ---------------------------------------------------------------------------
// persist_kernel — R8 structure with conflict-free LDS h layout:
//  bid 0..7  : L0  (Whh0 + cell0; h0 -> LDS + h0g; publishes l0p /4 steps)
//  bid 8..15 : Z1  (z1 = b1 + Wih1.h0 from h0g, 4-step windows -> z1f ring)
//  bid 16..23: L1  (Whh1 + cell1 + pool; consumes z1f ring)
//  bid 24..  : conv+x0 producers (x0 ring, BP on coarse flag)
// All hot flags one per 64B line: base + b16*16.
// ---------------------------------------------------------------------------
__global__ __launch_bounds__(512, 2) void persist_kernel(
    const float* __restrict__ x, const float* __restrict__ conv_w,
    const float* __restrict__ conv_b, const float* __restrict__ b_ih0,
    const float* __restrict__ b_hh0,
    const uint4* __restrict__ Wf0, const uint4* __restrict__ Wih1f,
    const uint4* __restrict__ Whh1f, const uint4* __restrict__ WB0f,
    const f32x4* __restrict__ b1fD,
    uint4* __restrict__ x0f, uint2* __restrict__ h0g, uint4* __restrict__ z1f,
    f32x4* __restrict__ psave, int* __restrict__ flags,
    int rmask, int rmask2) {
  __shared__ __align__(16) union {
    struct { float xs[34 * 16]; _Float16 yF[4096]; _Float16 x0S[32 * 512]; } wk;
    struct { _Float16 h[2][2048]; } rc;
  } sm;

  int* xready = flags;          // [tile*8 + b16], 512 ints
  int* l0p = flags + 512;       // + b16*16
  int* l0c = flags + 640;       // + b16*16
  int* z1p = flags + 768;       // + b16*16
  int* l1p = flags + 896;       // + b16*16

  const int bid = blockIdx.x;
  const int tid = threadIdx.x;
  const int w = tid >> 6, L = tid & 63, q = L >> 4, n = L & 15;

  if (bid < 8) {
    // ---------------- L0: layer-0 recurrence ----------------
    const int b16 = bid;
    half8 WA0[4][4];
#pragma unroll
    for (int tl = 0; tl < 4; ++tl)
#pragma unroll
      for (int s = 0; s < 4; ++s)
        WA0[tl][s] = __builtin_bit_cast(half8, Wf0[((w * 4 + tl) * 4 + s) * 64 + L]);

    f32x4 c0v = {0.f, 0.f, 0.f, 0.f};
    const int hoff = h_write_off(w, q, n);
    *(uint2*)&sm.rc.h[1][hoff] = make_uint2(0u, 0u);
    __syncthreads();

    const uint4* xp = x0f + (((size_t)b16 * 8 + w) * 64 + L) * 2;
    uint2* hg = h0g + ((b16 * 16 + n) * 32 + w * 4 + q);
    uint4 pa[4], pb[4];

    for (int g = 0; g < 64; ++g) {
      if (tid == 0) {
        while (__hip_atomic_load(&xready[g * 8 + b16], __ATOMIC_ACQUIRE,
                                 __HIP_MEMORY_SCOPE_AGENT) < 16)
          __builtin_amdgcn_s_sleep(2);
        if (g < 63)
          while (__hip_atomic_load(&xready[(g + 1) * 8 + b16], __ATOMIC_ACQUIRE,
                                   __HIP_MEMORY_SCOPE_AGENT) < 16)
            __builtin_amdgcn_s_sleep(2);
      }
      __syncthreads();
      if (g == 0) {
#pragma unroll
        for (int k = 0; k < 4; ++k) {
          pa[k] = xp[(size_t)k * 8192];
          pb[k] = xp[(size_t)k * 8192 + 1];
        }
      }
#pragma unroll 1
      for (int io = 0; io < 8; ++io) {
#pragma unroll
        for (int k = 0; k < 4; ++k) {
          const int t = g * 32 + io * 4 + k;
          const int c = t & 1, p = c ^ 1;
          f32x4 acc[4];
          {
            half8 xlo = __builtin_bit_cast(half8, pa[k]);
            half8 xhi = __builtin_bit_cast(half8, pb[k]);
            acc[0] = (f32x4){(float)xlo[0], (float)xlo[1], (float)xlo[2], (float)xlo[3]};
            acc[1] = (f32x4){(float)xlo[4], (float)xlo[5], (float)xlo[6], (float)xlo[7]};
            acc[2] = (f32x4){(float)xhi[0], (float)xhi[1], (float)xhi[2], (float)xhi[3]};
            acc[3] = (f32x4){(float)xhi[4], (float)xhi[5], (float)xhi[6], (float)xhi[7]};
          }
          half8 B0[4];
#pragma unroll
          for (int s = 0; s < 4; ++s)
            B0[s] = *(const half8*)&sm.rc.h[p][((s * 4 + q) * 16 + n) * 8];
#pragma unroll
          for (int s = 0; s < 4; ++s)
#pragma unroll
            for (int tl = 0; tl < 4; ++tl)
              acc[tl] = __builtin_amdgcn_mfma_f32_16x16x32_f16(WA0[tl][s], B0[s], acc[tl], 0, 0, 0);

          {
            int tn = t + 4; if (tn > T_ - 1) tn = T_ - 1;
            const size_t so = (size_t)(tn & rmask) * 8192;
            pa[k] = xp[so];
            pb[k] = xp[so + 1];
          }

          float h0v[4];
          lstm_cell(acc, c0v, h0v);
          uint2 h0p;
          h0p.x = packh2f(h0v[0], h0v[1]);
          h0p.y = packh2f(h0v[2], h0v[3]);
          *(uint2*)&sm.rc.h[c][hoff] = h0p;
          hg[(size_t)t * 4096] = h0p;

          __syncthreads();  // drains vmcnt (h0g store + prefetch)
          if (k == 3 && tid == 0)
            __hip_atomic_store(&l0p[b16 * 16], t + 1, __ATOMIC_RELEASE,
                               __HIP_MEMORY_SCOPE_AGENT);
        }
      }
      if (tid == 0)
        __hip_atomic_store(&l0c[b16 * 16], g * 32 + 32, __ATOMIC_RELAXED,
                           __HIP_MEMORY_SCOPE_AGENT);
    }
  } else if (bid < 16) {
    // ---------------- Z1: z1(t) = b1 + Wih1 . h0(t) ----------------
    const int b16 = bid - 8;
    half8 WI[4][4];
#pragma unroll
    for (int tl = 0; tl < 4; ++tl)
#pragma unroll
      for (int s = 0; s < 4; ++s)
        WI[tl][s] = __builtin_bit_cast(half8, Wih1f[((w * 4 + tl) * 4 + s) * 64 + L]);
    f32x4 b1v[4];
#pragma unroll
    for (int tl = 0; tl < 4; ++tl) b1v[tl] = b1fD[(w * 64 + L) * 4 + tl];

    const int n2 = tid >> 5, jq = tid & 31;
    // staging dest in new layout: j = jq*4 -> s=jq>>3, q_r=(jq>>1)&3, r=(jq&1)*4
    const int zoff = (((jq >> 3) * 4 + ((jq >> 1) & 3)) * 16 + n2) * 8 + (jq & 1) * 4;
    const uint2* hsrc = h0g + ((b16 * 16 + n2) * 32 + jq);
    uint4* zdst = z1f + (((size_t)b16 * 8 + w) * 64 + L) * 2;
    const int R2 = rmask2 + 1;
    uint2 hpf[4];

#pragma unroll 1
    for (int p0 = 0; p0 < T_; p0 += 4) {
      if (tid == 0) {
        while (__hip_atomic_load(&l0p[b16 * 16], __ATOMIC_ACQUIRE,
                                 __HIP_MEMORY_SCOPE_AGENT) < p0 + 4)
          __builtin_amdgcn_s_sleep(1);
        if (p0 + 4 > R2) {
          const int need = p0 + 12 - R2;  // z1-ring WAR margin
          while (__hip_atomic_load(&l1p[b16 * 16], __ATOMIC_RELAXED,
                                   __HIP_MEMORY_SCOPE_AGENT) < need)
            __builtin_amdgcn_s_sleep(8);
        }
      }
      __syncthreads();
#pragma unroll
      for (int k = 0; k < 4; ++k) hpf[k] = hsrc[(size_t)(p0 + k) * 4096];
#pragma unroll
      for (int k = 0; k < 4; ++k) {
        const int t = p0 + k;
        const int c = t & 1;
        *(uint2*)&sm.rc.h[c][zoff] = hpf[k];
        __syncthreads();
        half8 B[4];
#pragma unroll
        for (int s = 0; s < 4; ++s)
          B[s] = *(const half8*)&sm.rc.h[c][((s * 4 + q) * 16 + n) * 8];
        f32x4 acc[4];
#pragma unroll
        for (int tl = 0; tl < 4; ++tl) acc[tl] = b1v[tl];
#pragma unroll
        for (int s = 0; s < 4; ++s)
#pragma unroll
          for (int tl = 0; tl < 4; ++tl)
            acc[tl] = __builtin_amdgcn_mfma_f32_16x16x32_f16(WI[tl][s], B[s], acc[tl], 0, 0, 0);
        uint4 o0, o1;
        o0.x = packh2f(acc[0][0], acc[0][1]); o0.y = packh2f(acc[0][2], acc[0][3]);
        o0.z = packh2f(acc[1][0], acc[1][1]); o0.w = packh2f(acc[1][2], acc[1][3]);
        o1.x = packh2f(acc[2][0], acc[2][1]); o1.y = packh2f(acc[2][2], acc[2][3]);
        o1.z = packh2f(acc[3][0], acc[3][1]); o1.w = packh2f(acc[3][2], acc[3][3]);
        const size_t zs = (size_t)(t & rmask2) * 8192;
        zdst[zs] = o0;
        zdst[zs + 1] = o1;
      }
      vmdrain();     // z1 stores visible before publish
      __syncthreads();
      if (tid == 0)
        __hip_atomic_store(&z1p[b16 * 16], p0 + 4, __ATOMIC_RELEASE,
                           __HIP_MEMORY_SCOPE_AGENT);
    }
  } else if (bid < 24) {
    // ---------------- L1: layer-1 recurrence (Whh1 only) ----------------
    const int b16 = bid - 16;
    half8 WH[4][4];
#pragma unroll
    for (int tl = 0; tl < 4; ++tl)
#pragma unroll
      for (int s = 0; s < 4; ++s)
        WH[tl][s] = __builtin_bit_cast(half8, Whh1f[((w * 4 + tl) * 4 + s) * 64 + L]);

    f32x4 c1v = {0.f, 0.f, 0.f, 0.f};
    f32x4 pool = {0.f, 0.f, 0.f, 0.f};
    const int hoff = h_write_off(w, q, n);
    *(uint2*)&sm.rc.h[1][hoff] = make_uint2(0u, 0u);
    __syncthreads();

    const uint4* zp = z1f + (((size_t)b16 * 8 + w) * 64 + L) * 2;
    uint4 pa[4], pb[4];

#pragma unroll 1
    for (int g4 = 0; g4 < 512; ++g4) {
      const int p0 = g4 * 4;
      if (tid == 0) {
        int tgt = p0 + 8; if (tgt > T_) tgt = T_;
        while (__hip_atomic_load(&z1p[b16 * 16], __ATOMIC_ACQUIRE,
                                 __HIP_MEMORY_SCOPE_AGENT) < tgt)
          __builtin_amdgcn_s_sleep(1);
      }
      __syncthreads();
      if (g4 == 0) {
#pragma unroll
        for (int k = 0; k < 4; ++k) {
          pa[k] = zp[(size_t)k * 8192];
          pb[k] = zp[(size_t)k * 8192 + 1];
        }
      }
#pragma unroll
      for (int k = 0; k < 4; ++k) {
        const int t = p0 + k;
        const int c = t & 1, p = c ^ 1;
        f32x4 acc[4];
        {
          half8 xlo = __builtin_bit_cast(half8, pa[k]);
          half8 xhi = __builtin_bit_cast(half8, pb[k]);
          acc[0] = (f32x4){(float)xlo[0], (float)xlo[1], (float)xlo[2], (float)xlo[3]};
          acc[1] = (f32x4){(float)xlo[4], (float)xlo[5], (float)xlo[6], (float)xlo[7]};
          acc[2] = (f32x4){(float)xhi[0], (float)xhi[1], (float)xhi[2], (float)xhi[3]};
          acc[3] = (f32x4){(float)xhi[4], (float)xhi[5], (float)xhi[6], (float)xhi[7]};
        }
        half8 B1[4];
#pragma unroll
        for (int s = 0; s < 4; ++s)
          B1[s] = *(const half8*)&sm.rc.h[p][((s * 4 + q) * 16 + n) * 8];
#pragma unroll
        for (int s = 0; s < 4; ++s)
#pragma unroll
          for (int tl = 0; tl < 4; ++tl)
            acc[tl] = __builtin_amdgcn_mfma_f32_16x16x32_f16(WH[tl][s], B1[s], acc[tl], 0, 0, 0);

        {
          int tn = t + 4; if (tn > T_ - 1) tn = T_ - 1;
          const size_t so = (size_t)(tn & rmask2) * 8192;
          pa[k] = zp[so];
          pb[k] = zp[so + 1];
        }

        float h1v[4];
        lstm_cell(acc, c1v, h1v);
        pool[0] += h1v[0]; pool[1] += h1v[1];
        pool[2] += h1v[2]; pool[3] += h1v[3];
        uint2 h1p;
        h1p.x = packh2f(h1v[0], h1v[1]);
        h1p.y = packh2f(h1v[2], h1v[3]);
        *(uint2*)&sm.rc.h[c][hoff] = h1p;
        __syncthreads();
      }
      if ((g4 & 1) && tid == 0)
        __hip_atomic_store(&l1p[b16 * 16], p0 + 4, __ATOMIC_RELEASE,
                           __HIP_MEMORY_SCOPE_AGENT);
    }
    psave[(b16 * 8 + w) * 64 + L] = pool;
  } else {
    // ---------------- conv + x0 projection workers ----------------
    const int wi = bid - 24;
    const int co = tid & 127;
    float cw[48];
#pragma unroll
    for (int i = 0; i < 12; ++i) {
      const float4 v = *(const float4*)(conv_w + co * 48 + i * 4);
      cw[i * 4 + 0] = v.x; cw[i * 4 + 1] = v.y;
      cw[i * 4 + 2] = v.z; cw[i * 4 + 3] = v.w;
    }
    const float cb = conv_b[co];
    // conv-out scatter offset in yF layout [s][q][row 32][8]:
    const int ywoff = (((co >> 5) * 4 + ((co >> 3) & 3)) * 32) * 8 + (co & 7);
    half8 WB[4][4];
#pragma unroll
    for (int nt4 = 0; nt4 < 4; ++nt4)
#pragma unroll
      for (int s = 0; s < 4; ++s)
        WB[nt4][s] = __builtin_bit_cast(half8, WB0f[((w * 4 + nt4) * 4 + s) * 64 + L]);
    float b0v[4];
#pragma unroll
    for (int nt4 = 0; nt4 < 4; ++nt4) {
      int gg = (w * 4 + nt4) * 16 + n;
      b0v[nt4] = (b_ih0[gg] + b_hh0[gg]) * (((gg >> 7) == 2) ? L2E2 : L2E);
    }
    const int R = rmask + 1;

    for (int u = wi; u < 8192; u += WCV) {
      const int tile = u >> 7, b = u & 127;
      const int t0c = tile * 32;
      if (t0c + 40 > R) {
        const int need = t0c + 40 - R;
        if (tid == 0)
          while (__hip_atomic_load(&l0c[(b >> 4) * 16], __ATOMIC_RELAXED,
                                   __HIP_MEMORY_SCOPE_AGENT) < need)
            __builtin_amdgcn_s_sleep(8);
      }
      __syncthreads();

      for (int idx = tid; idx < 544; idx += 512) {
        int row = idx >> 4, cc2 = idx & 15;
        int gt = t0c - 1 + row;
        sm.wk.xs[idx] = (gt >= 0 && gt < T_) ? x[((size_t)b * T_ + gt) * C_ + cc2] : 0.f;
      }
      __syncthreads();

#pragma unroll
      for (int pp = 0; pp < 8; ++pp) {
        int r = pp * 4 + (tid >> 7);
        float acc = cb;
#pragma unroll
        for (int c16 = 0; c16 < 16; ++c16)
#pragma unroll
          for (int kk = 0; kk < 3; ++kk)
            acc += sm.wk.xs[(r + kk) * 16 + c16] * cw[c16 * 3 + kk];
        acc = acc >= 0.f ? acc : 0.01f * acc;
        sm.wk.yF[ywoff + r * 8] = (_Float16)acc;
      }
      __syncthreads();

#pragma unroll
      for (int mt = 0; mt < 2; ++mt) {
        half8 A[4];
#pragma unroll
        for (int s = 0; s < 4; ++s)
          A[s] = *(const half8*)&sm.wk.yF[((s * 4 + q) * 32 + mt * 16 + n) * 8];
#pragma unroll
        for (int nt4 = 0; nt4 < 4; ++nt4) {
          f32x4 acc = {b0v[nt4], b0v[nt4], b0v[nt4], b0v[nt4]};
#pragma unroll
          for (int s = 0; s < 4; ++s)
            acc = __builtin_amdgcn_mfma_f32_16x16x32_f16(A[s], WB[nt4][s], acc, 0, 0, 0);
          int tau = w * 4 + nt4;
          int off = (tau & 7) * 64 + (n >> 2) * 16 + (tau >> 3) * 4 + (n & 3);
#pragma unroll
          for (int reg = 0; reg < 4; ++reg)
            sm.wk.x0S[(mt * 16 + q * 4 + reg) * 512 + off] = (_Float16)acc[reg];
        }
      }
      __syncthreads();

      const int bn = b & 15, bb16 = b >> 4;
      const int trb = t0c & rmask;
#pragma unroll
      for (int kk = 0; kk < 2; ++kk) {
        int cc = kk * 512 + tid;
        int r = cc >> 5, wq = cc & 31;
        int w2 = wq >> 2, q2 = wq & 3;
        const uint4* src = (const uint4*)&sm.wk.x0S[r * 512 + wq * 16];
        size_t gidx = ((((size_t)(trb + r) * 8 + bb16) * 8 + w2) * 64 + (bn + 16 * q2)) * 2;
        x0f[gidx] = src[0];
        x0f[gidx + 1] = src[1];
      }
      vmdrain();
      __syncthreads();
      if (tid == 0)
        __hip_atomic_fetch_add(&xready[tile * 8 + bb16], 1, __ATOMIC_RELEASE,
                               __HIP_MEMORY_SCOPE_AGENT);
    }
  }
}

// ---------------------------------------------------------------------------
__global__ __launch_bounds__(128) void final_kernel(
    const f32x4* __restrict__ psave, const float* __restrict__ lin_w,
    const float* __restrict__ lin_b, float* __restrict__ out) {
  int b = threadIdx.x;
  int n = b & 15, b16 = b >> 4;
  float acc = 0.f;
  for (int w = 0; w < 8; ++w)
#pragma unroll
    for (int q = 0; q < 4; ++q) {
      f32x4 v = psave[(b16 * 8 + w) * 64 + n + 16 * q];
#pragma unroll
      for (int reg = 0; reg < 4; ++reg)
        acc += v[reg] * lin_w[w * 16 + q * 4 + reg];
    }
  out[b] = acc * (1.0f / (float)T_) + lin_b[0];
}

// ---------------------------------------------------------------------------
extern "C" void kernel_launch(void* const* d_in, const int* in_sizes, int n_in,
                              void* d_out, int out_size, void* d_ws, size_t ws_size,
                              hipStream_t stream) {
  (void)in_sizes; (void)n_in; (void)out_size;
  const float* x      = (const float*)d_in[0];
  const float* conv_w = (const float*)d_in[1];
  const float* conv_b = (const float*)d_in[2];
  const float* w_ih0  = (const float*)d_in[3];
  const float* w_hh0  = (const float*)d_in[4];
  const float* b_ih0  = (const float*)d_in[5];
  const float* b_hh0  = (const float*)d_in[6];
  const float* w_ih1  = (const float*)d_in[7];
  const float* w_hh1  = (const float*)d_in[8];
  const float* b_ih1  = (const float*)d_in[9];
  const float* b_hh1  = (const float*)d_in[10];
  const float* lin_w  = (const float*)d_in[11];
  const float* lin_b  = (const float*)d_in[12];

  char* ws = (char*)d_ws;
  uint4* Wf0   = (uint4*)(ws + 0);        // 131072
  uint4* Wih1f = (uint4*)(ws + 131072);   // 131072
  uint4* Whh1f = (uint4*)(ws + 262144);   // 131072
  uint4* WB0f  = (uint4*)(ws + 393216);   // 131072
  f32x4* b1fD  = (f32x4*)(ws + 524288);   // 32768
  f32x4* psave = (f32x4*)(ws + 557056);   // 65536
  int*   flags = (int*)(ws + 622592);     // 4096 (1024 ints, line-padded)
  uint2* h0g   = (uint2*)(ws + 626688);   // 67108864 (full-T h0 stream)
  const size_t base = 626688 + 67108864;  // 67735552

  int R = 256, R2 = 256;  // x0 ring, z1 ring (steps)
  while (R > 64 && base + ((size_t)R + (size_t)R2) * 131072 > ws_size) {
    R >>= 1; R2 >>= 1;
  }
  uint4* x0f = (uint4*)(ws + base);
  uint4* z1f = (uint4*)(ws + base + (size_t)R * 131072);

  hipMemsetAsync(flags, 0, 4096, stream);
  pack_kernel<<<136, 256, 0, stream>>>(w_ih0, w_hh0, w_ih1, w_hh1, b_ih1, b_hh1,
                                       Wf0, Wih1f, Whh1f, WB0f, b1fD);
  persist_kernel<<<NBLK, 512, 0, stream>>>(
      x, conv_w, conv_b, b_ih0, b_hh0, Wf0, Wih1f, Whh1f, WB0f, b1fD,
      x0f, h0g, z1f, psave, flags, R - 1, R2 - 1);
  final_kernel<<<1, 128, 0, stream>>>(psave, lin_w, lin_b, (float*)d_out);
}